// Round 11
// baseline (478.117 us; speedup 1.0000x reference)
//
#include <hip/hip_runtime.h>
#include <hip/hip_bf16.h>
#include <hip/hip_cooperative_groups.h>
#include <math.h>

namespace cg = cooperative_groups;

#define NB 8
#define HH 1024
#define WW 1280
#define HW (HH*WW)            // 1310720
#define N4 (HW/4)             // 327680
#define LBINS 2048
#define HBINS 2048
#define NSCENE 8
#define EPSF 1e-8f
#define CAPMAX 8192
#define HBLK 64               // hist/collect blocks per sample
#define SGRID (NB*HBLK)       // 512 blocks, co-resident (2/CU)

typedef float f32x4 __attribute__((ext_vector_type(4)));

// ws layout (32-bit word offsets) — no pre-zeroing required anywhere
#define WS_PART    0                          // NB*HBLK*HBINS u32 (plain stores)
#define WS_PMAX    (WS_PART + NB*HBLK*HBINS)  // NB*HBLK f32 per-block maxes
#define WS_INFO    (WS_PMAX + NB*HBLK)        // NB*4 u32 {t1, t2, jrel, pad}
#define WS_LOHI    (WS_INFO + NB*4)           // NB*2 f32 {lo, hi}
#define WS_LUT     (WS_LOHI + NB*2)           // 2048 f32
#define WS_CNT     (WS_LUT + LBINS)           // NB u32 (zeroed in phase B)
#define WS_COLLECT (WS_CNT + NB)              // NB*cap f32

__device__ __forceinline__ unsigned fkey(float f) {
    unsigned u = __float_as_uint(f);
    return (u & 0x80000000u) ? ~u : (u | 0x80000000u);
}
__device__ __forceinline__ float keyf(unsigned k) {
    unsigned u = (k & 0x80000000u) ? (k & 0x7fffffffu) : ~k;
    return __uint_as_float(u);
}

// Cooperative stats kernel: hist -> scan/lut -> collect -> select, one launch.
// 512 blocks x 256 threads; shared 35KB arena reused across phases (4 blocks/CU).
__global__ __launch_bounds__(256) void k_stats(const float* __restrict__ x,
                                               const float* __restrict__ delta,
                                               unsigned* __restrict__ ws, int cap) {
    cg::grid_group grid = cg::this_grid();
    __shared__ unsigned smem[8709];   // select needs 8192+256+256+5
    const int tid = threadIdx.x;
    const int s64 = blockIdx.x >> 6;   // sample for A/C
    const int b64 = blockIdx.x & 63;   // sub-block for A/C

    // ---- Phase A: per-sample 2048-bin histogram + block max ----
    {
        unsigned* lh = smem;
        float* redf = (float*)(smem + HBINS);
        for (int i = tid; i < HBINS; i += 256) lh[i] = 0u;
        __syncthreads();
        const float4* xs = (const float4*)(x + (size_t)s64 * HW);
        float mx = -3.4e38f;
        for (int i = b64 * 256 + tid; i < N4; i += HBLK * 256) {
            float4 v = xs[i];
            float fv[4] = {v.x, v.y, v.z, v.w};
#pragma unroll
            for (int c = 0; c < 4; ++c) {
                float f = fv[c];
                int b = (int)(f * 2048.0f);
                b = b < 0 ? 0 : (b > 2047 ? 2047 : b);
                atomicAdd(&lh[b], 1u);
                mx = fmaxf(mx, f);
            }
        }
        for (int d = 32; d > 0; d >>= 1) mx = fmaxf(mx, __shfl_down(mx, d));
        if ((tid & 63) == 0) redf[tid >> 6] = mx;
        __syncthreads();
        unsigned* myp = ws + WS_PART + ((size_t)s64 * HBLK + b64) * HBINS;
        for (int i = tid; i < HBINS; i += 256) myp[i] = lh[i];
        if (tid == 0) {
            float m2 = fmaxf(fmaxf(redf[0], redf[1]), fmaxf(redf[2], redf[3]));
            ((float*)(ws + WS_PMAX))[s64 * HBLK + b64] = m2;
        }
    }
    grid.sync();

    // ---- Phase B: blocks 0..7 scan; block 8 LUT ----
    if (blockIdx.x == NB) {
        float* sf = (float*)smem;
        float inc[8];
        float run = 0.0f;
#pragma unroll
        for (int i = 0; i < 8; ++i) {
            int j = tid * 8 + i;
            float ssum = 0.0f;
#pragma unroll
            for (int sc = 0; sc < NSCENE; ++sc) ssum += delta[sc * LBINS + j];
            float v = ssum * 0.125f;
            run += fmaxf(v, 0.0f) + log1pf(expf(-fabsf(v))) + EPSF;   // softplus+eps
            inc[i] = run;   // local inclusive
        }
        sf[tid] = run;
        __syncthreads();
        for (int d = 1; d < 256; d <<= 1) {   // Hillis-Steele over thread totals
            float add = (tid >= d) ? sf[tid - d] : 0.0f;
            __syncthreads();
            sf[tid] += add;
            __syncthreads();
        }
        float excl = sf[tid] - run;
        float total = sf[255];
        float* lut = (float*)(ws + WS_LUT);
#pragma unroll
        for (int i = 0; i < 8; ++i)
            lut[tid * 8 + i] = (excl + inc[i]) / (total + EPSF) * 2.0f - 1.0f;
    } else if (blockIdx.x < NB) {
        const int s = blockIdx.x;
        unsigned* su = smem;
        const unsigned* part = ws + WS_PART + (size_t)s * HBLK * HBINS;
        unsigned cnt[8];
        unsigned run = 0u;
#pragma unroll
        for (int i = 0; i < 8; ++i) {
            int j = tid * 8 + i;
            unsigned c = 0;
            for (int b = 0; b < HBLK; ++b) c += part[b * HBINS + j];
            cnt[i] = c;
            run += c;
        }
        su[tid] = run;
        __syncthreads();
        for (int d = 1; d < 256; d <<= 1) {
            unsigned add = (tid >= d) ? su[tid - d] : 0u;
            __syncthreads();
            su[tid] += add;
            __syncthreads();
        }
        unsigned before = su[tid] - run;
        const float idxf = 0.02f * (float)(HW - 1);   // f32, mirrors JAX
        const unsigned k = (unsigned)idxf;            // 26214
#pragma unroll
        for (int i = 0; i < 8; ++i) {
            unsigned c = cnt[i];
            unsigned bin = tid * 8 + i;
            if (before <= k && k < before + c) {
                ws[WS_INFO + s * 4 + 0] = bin;
                ws[WS_INFO + s * 4 + 2] = k - before;
            }
            if (before <= k + 1 && k + 1 < before + c) {
                ws[WS_INFO + s * 4 + 1] = bin;
            }
            before += c;
        }
        if (tid < 64) {   // wave 0: reduce block maxes -> hi
            float mx = ((const float*)(ws + WS_PMAX))[s * HBLK + tid];
            for (int d = 32; d > 0; d >>= 1) mx = fmaxf(mx, __shfl_down(mx, d));
            if (tid == 0) {
                ((float*)(ws + WS_LOHI))[s * 2 + 1] = mx;
                ws[WS_CNT + s] = 0u;
            }
        }
    }
    grid.sync();

    // ---- Phase C: collect candidates in [t1,t2] (x is L3-resident) ----
    {
        const unsigned t1 = ws[WS_INFO + s64 * 4 + 0];
        const unsigned t2 = ws[WS_INFO + s64 * 4 + 1];
        float* coll = (float*)(ws + WS_COLLECT) + (size_t)s64 * cap;
        unsigned* cnt = ws + WS_CNT + s64;
        const float4* xs = (const float4*)(x + (size_t)s64 * HW);
        for (int i = b64 * 256 + tid; i < N4; i += HBLK * 256) {
            float4 v = xs[i];
            float fv[4] = {v.x, v.y, v.z, v.w};
#pragma unroll
            for (int c = 0; c < 4; ++c) {
                float f = fv[c];
                int b = (int)(f * 2048.0f);
                b = b < 0 ? 0 : (b > 2047 ? 2047 : b);
                if ((unsigned)b >= t1 && (unsigned)b <= t2) {
                    unsigned p = atomicAdd(cnt, 1u);
                    if (p < (unsigned)cap) coll[p] = f;
                }
            }
        }
    }
    grid.sync();

    // ---- Phase D: blocks 0..7 radix-select -> lo ----
    if (blockIdx.x < NB) {
        const int s = blockIdx.x;
        unsigned* keys = smem;
        unsigned* hist = smem + CAPMAX;
        unsigned* pfx  = smem + CAPMAX + 256;
        unsigned* sc   = smem + CAPMAX + 512;   // {bucket, r, L, E, mg}
        unsigned m = ws[WS_CNT + s];
        if (m > (unsigned)cap) m = (unsigned)cap;
        const float* coll = (const float*)(ws + WS_COLLECT) + (size_t)s * cap;
        const unsigned jrel = ws[WS_INFO + s * 4 + 2];

        for (unsigned i = tid; i < m; i += 256) keys[i] = fkey(coll[i]);
        if (tid == 0) { sc[2] = 0; sc[3] = 0; sc[4] = 0xFFFFFFFFu; }
        __syncthreads();

        unsigned prefix = 0;
        unsigned r = jrel;
        for (int shift = 24; shift >= 0; shift -= 8) {
            hist[tid] = 0u;
            __syncthreads();
            for (unsigned i = tid; i < m; i += 256) {
                unsigned kk = keys[i];
                bool ok = (shift == 24) || ((kk >> (shift + 8)) == prefix);
                if (ok) atomicAdd(&hist[(kk >> shift) & 255u], 1u);
            }
            __syncthreads();
            if (tid < 64) {
                unsigned a0 = hist[tid*4+0], a1 = hist[tid*4+1];
                unsigned a2 = hist[tid*4+2], a3 = hist[tid*4+3];
                unsigned sum = a0 + a1 + a2 + a3;
                unsigned incv = sum;
                for (int d = 1; d < 64; d <<= 1) {
                    unsigned y = __shfl_up(incv, d);
                    if (tid >= d) incv += y;
                }
                unsigned excl = incv - sum;
                pfx[tid*4+0] = excl;
                pfx[tid*4+1] = excl + a0;
                pfx[tid*4+2] = excl + a0 + a1;
                pfx[tid*4+3] = excl + a0 + a1 + a2;
            }
            __syncthreads();
            {
                unsigned e = pfx[tid], c = hist[tid];
                if (e <= r && r < e + c) { sc[0] = tid; sc[1] = r - e; }
            }
            __syncthreads();
            prefix = (prefix << 8) | sc[0];
            r = sc[1];
            __syncthreads();
        }
        const unsigned vk = prefix;
        unsigned lL = 0, lE = 0, lmg = 0xFFFFFFFFu;
        for (unsigned i = tid; i < m; i += 256) {
            unsigned kk = keys[i];
            lL += (kk < vk) ? 1u : 0u;
            lE += (kk == vk) ? 1u : 0u;
            if (kk > vk && kk < lmg) lmg = kk;
        }
        atomicAdd(&sc[2], lL);
        atomicAdd(&sc[3], lE);
        atomicMin(&sc[4], lmg);
        __syncthreads();
        if (tid == 0) {
            unsigned vk1 = (jrel + 1 < sc[2] + sc[3]) ? vk : sc[4];
            float svk = keyf(vk), svk1 = keyf(vk1);
            const float idxf = 0.02f * (float)(HW - 1);
            const float frac = idxf - (float)((unsigned)idxf);   // 0.380859375
            ((float*)(ws + WS_LOHI))[s * 2 + 0] = svk * (1.0f - frac) + svk1 * frac;
        }
    }
}

// main transform: normalize -> bin -> LUT gather -> write 3 channels (nontemporal)
__global__ __launch_bounds__(256) void k_apply(const float* __restrict__ x,
                                               const unsigned* __restrict__ ws,
                                               float* __restrict__ y) {
    __shared__ float slut[LBINS];
    const float* lutg = (const float*)(ws + WS_LUT);
    for (int i = threadIdx.x; i < LBINS; i += 256) slut[i] = lutg[i];
    const int s = blockIdx.y;
    const float* lh = (const float*)(ws + WS_LOHI);
    const float lo = lh[s * 2 + 0];
    const float hi = lh[s * 2 + 1];
    const float denom = hi - lo + EPSF;
    __syncthreads();
    const f32x4* xs = (const f32x4*)(x + (size_t)s * HW);
    f32x4* y0 = (f32x4*)(y + (size_t)s * 3 * HW);
    f32x4* y1 = (f32x4*)(y + (size_t)s * 3 * HW + HW);
    f32x4* y2 = (f32x4*)(y + (size_t)s * 3 * HW + 2 * HW);
    for (int i = blockIdx.x * 256 + threadIdx.x; i < N4; i += gridDim.x * 256) {
        f32x4 v = xs[i];
        f32x4 o;
#pragma unroll
        for (int c = 0; c < 4; ++c) {
            float xn = (v[c] - lo) / denom;
            xn = xn < 0.0f ? 0.0f : (xn > 1.0f ? 1.0f : xn);
            float t = xn * 2047.0f;
            int idx = (int)t;
            idx = idx < 0 ? 0 : (idx > 2047 ? 2047 : idx);
            o[c] = slut[idx];
        }
        __builtin_nontemporal_store(o, &y0[i]);
        __builtin_nontemporal_store(o, &y1[i]);
        __builtin_nontemporal_store(o, &y2[i]);
    }
}

extern "C" void kernel_launch(void* const* d_in, const int* in_sizes, int n_in,
                              void* d_out, int out_size, void* d_ws, size_t ws_size,
                              hipStream_t stream) {
    const float* x = (const float*)d_in[0];
    const float* delta = (const float*)d_in[1];
    float* y = (float*)d_out;
    unsigned* ws = (unsigned*)d_ws;

    int cap = CAPMAX;
    size_t avail_words = ws_size / 4;
    size_t per_sample = avail_words > WS_COLLECT ? (avail_words - WS_COLLECT) / NB : 0;
    if ((size_t)cap > per_sample) cap = (int)per_sample;

    void* args[] = {(void*)&x, (void*)&delta, (void*)&ws, (void*)&cap};
    hipLaunchCooperativeKernel((const void*)k_stats, dim3(SGRID), dim3(256),
                               args, 0, stream);
    k_apply<<<dim3(320, NB), dim3(256), 0, stream>>>(x, ws, y);
}

// Round 12
// 295.696 us; speedup vs baseline: 1.6169x; 1.6169x over previous
//
#include <hip/hip_runtime.h>
#include <hip/hip_bf16.h>
#include <math.h>

#define NB 8
#define HH 1024
#define WW 1280
#define HW (HH*WW)            // 1310720
#define N4 (HW/4)             // 327680
#define LBINS 2048
#define HBINS 2048
#define NSCENE 8
#define EPSF 1e-8f
#define CAPMAX 8192
#define HBLK 64               // hist/collect blocks per sample

typedef float f32x4 __attribute__((ext_vector_type(4)));

// ws layout (32-bit word offsets) — no pre-zeroing required anywhere
#define WS_PART    0                          // NB*HBLK*HBINS u32 (plain stores)
#define WS_PMAX    (WS_PART + NB*HBLK*HBINS)  // NB*HBLK f32 per-block maxes
#define WS_INFO    (WS_PMAX + NB*HBLK)        // NB*4 u32 {t1, t2, jrel, pad}
#define WS_LOHI    (WS_INFO + NB*4)           // NB*2 f32 {lo, hi}
#define WS_LUT     (WS_LOHI + NB*2)           // 2048 f32
#define WS_CNT     (WS_LUT + LBINS)           // NB u32 (zeroed by k_scan_lut)
#define WS_COLLECT (WS_CNT + NB)              // NB*cap f32

__device__ __forceinline__ unsigned fkey(float f) {
    unsigned u = __float_as_uint(f);
    return (u & 0x80000000u) ? ~u : (u | 0x80000000u);
}
__device__ __forceinline__ float keyf(unsigned k) {
    unsigned u = (k & 0x80000000u) ? (k & 0x7fffffffu) : ~k;
    return __uint_as_float(u);
}

// per-sample 2048-bin histogram + block max -> private partials.
// 512-thread blocks: 8 waves/block, 2 blocks/CU -> 50% occupancy for latency hiding.
__global__ __launch_bounds__(512) void k_hist(const float* __restrict__ x,
                                              unsigned* __restrict__ ws) {
    __shared__ unsigned lh[HBINS];
    __shared__ float redf[8];
    const int s = blockIdx.y;
    const int tid = threadIdx.x;
    for (int i = tid; i < HBINS; i += 512) lh[i] = 0u;
    __syncthreads();
    const float4* xs = (const float4*)(x + (size_t)s * HW);
    float mx = -3.4e38f;
    for (int i = blockIdx.x * 512 + tid; i < N4; i += HBLK * 512) {
        float4 v = xs[i];
        float fv[4] = {v.x, v.y, v.z, v.w};
#pragma unroll
        for (int c = 0; c < 4; ++c) {
            float f = fv[c];
            int b = (int)(f * 2048.0f);
            b = b < 0 ? 0 : (b > 2047 ? 2047 : b);
            atomicAdd(&lh[b], 1u);
            mx = fmaxf(mx, f);
        }
    }
    for (int d = 32; d > 0; d >>= 1) mx = fmaxf(mx, __shfl_down(mx, d));
    if ((tid & 63) == 0) redf[tid >> 6] = mx;
    __syncthreads();
    unsigned* myp = ws + WS_PART + ((size_t)s * HBLK + blockIdx.x) * HBINS;
    for (int i = tid; i < HBINS; i += 512) myp[i] = lh[i];
    if (tid == 0) {
        float m2 = redf[0];
#pragma unroll
        for (int w = 1; w < 8; ++w) m2 = fmaxf(m2, redf[w]);
        ((float*)(ws + WS_PMAX))[s * HBLK + blockIdx.x] = m2;
    }
}

// blocks 0..7: per-sample partial-sum + prefix-scan -> target bins, jrel, hi, cnt=0
// block 8: LUT (softplus of scene-mean -> cumsum -> normalize to [-1,1])
__global__ __launch_bounds__(256) void k_scan_lut(unsigned* __restrict__ ws,
                                                  const float* __restrict__ delta) {
    __shared__ unsigned su[256];
    __shared__ float sf[256];
    const int s = blockIdx.x;
    const int tid = threadIdx.x;
    if (s == NB) {
        float inc[8];
        float run = 0.0f;
#pragma unroll
        for (int i = 0; i < 8; ++i) {
            int j = tid * 8 + i;
            float ssum = 0.0f;
#pragma unroll
            for (int sc = 0; sc < NSCENE; ++sc) ssum += delta[sc * LBINS + j];
            float v = ssum * 0.125f;
            run += fmaxf(v, 0.0f) + log1pf(expf(-fabsf(v))) + EPSF;   // softplus+eps
            inc[i] = run;   // local inclusive
        }
        sf[tid] = run;
        __syncthreads();
        for (int d = 1; d < 256; d <<= 1) {   // Hillis-Steele over thread totals
            float add = (tid >= d) ? sf[tid - d] : 0.0f;
            __syncthreads();
            sf[tid] += add;
            __syncthreads();
        }
        float excl = sf[tid] - run;
        float total = sf[255];
        float* lut = (float*)(ws + WS_LUT);
#pragma unroll
        for (int i = 0; i < 8; ++i)
            lut[tid * 8 + i] = (excl + inc[i]) / (total + EPSF) * 2.0f - 1.0f;
        return;
    }
    // sum 64 partials per bin (8 consecutive bins per thread)
    const unsigned* part = ws + WS_PART + (size_t)s * HBLK * HBINS;
    unsigned cnt[8];
    unsigned run = 0u;
#pragma unroll
    for (int i = 0; i < 8; ++i) {
        int j = tid * 8 + i;
        unsigned c = 0;
        for (int b = 0; b < HBLK; ++b) c += part[b * HBINS + j];
        cnt[i] = c;
        run += c;
    }
    su[tid] = run;
    __syncthreads();
    for (int d = 1; d < 256; d <<= 1) {
        unsigned add = (tid >= d) ? su[tid - d] : 0u;
        __syncthreads();
        su[tid] += add;
        __syncthreads();
    }
    unsigned before = su[tid] - run;
    const float idxf = 0.02f * (float)(HW - 1);   // f32, mirrors JAX
    const unsigned k = (unsigned)idxf;            // 26214
#pragma unroll
    for (int i = 0; i < 8; ++i) {
        unsigned c = cnt[i];
        unsigned bin = tid * 8 + i;
        if (before <= k && k < before + c) {
            ws[WS_INFO + s * 4 + 0] = bin;
            ws[WS_INFO + s * 4 + 2] = k - before;   // rank of v[k] within collected
        }
        if (before <= k + 1 && k + 1 < before + c) {
            ws[WS_INFO + s * 4 + 1] = bin;
        }
        before += c;
    }
    if (tid < 64) {   // exactly wave 0: reduce block maxes -> hi
        float mx = ((const float*)(ws + WS_PMAX))[s * HBLK + tid];
        for (int d = 32; d > 0; d >>= 1) mx = fmaxf(mx, __shfl_down(mx, d));
        if (tid == 0) {
            ((float*)(ws + WS_LOHI))[s * 2 + 1] = mx;
            ws[WS_CNT + s] = 0u;
        }
    }
}

// gather elements in target bin range (x re-read is L2/L3-resident). 512-thread blocks.
__global__ __launch_bounds__(512) void k_collect(const float* __restrict__ x,
                                                 unsigned* __restrict__ ws, int cap) {
    const int s = blockIdx.y;
    const unsigned t1 = ws[WS_INFO + s * 4 + 0];
    const unsigned t2 = ws[WS_INFO + s * 4 + 1];
    float* coll = (float*)(ws + WS_COLLECT) + (size_t)s * cap;
    unsigned* cnt = ws + WS_CNT + s;
    const float4* xs = (const float4*)(x + (size_t)s * HW);
    for (int i = blockIdx.x * 512 + threadIdx.x; i < N4; i += HBLK * 512) {
        float4 v = xs[i];
        float fv[4] = {v.x, v.y, v.z, v.w};
#pragma unroll
        for (int c = 0; c < 4; ++c) {
            float f = fv[c];
            int b = (int)(f * 2048.0f);
            b = b < 0 ? 0 : (b > 2047 ? 2047 : b);
            if ((unsigned)b >= t1 && (unsigned)b <= t2) {
                unsigned p = atomicAdd(cnt, 1u);
                if (p < (unsigned)cap) coll[p] = f;
            }
        }
    }
}

// exact selection via 4-pass byte-radix, then v[k+1] pass; writes lo
__global__ __launch_bounds__(256) void k_select(unsigned* __restrict__ ws, int cap) {
    __shared__ unsigned keys[CAPMAX];
    __shared__ unsigned hist[256];
    __shared__ unsigned pfx[256];
    __shared__ unsigned s_bucket, s_r;
    __shared__ unsigned s_L, s_E, s_mg;
    const int s = blockIdx.x;
    const int tid = threadIdx.x;
    unsigned m = ws[WS_CNT + s];
    if (m > (unsigned)cap) m = (unsigned)cap;
    const float* coll = (const float*)(ws + WS_COLLECT) + (size_t)s * cap;
    const unsigned jrel = ws[WS_INFO + s * 4 + 2];

    for (unsigned i = tid; i < m; i += 256) keys[i] = fkey(coll[i]);
    if (tid == 0) { s_L = 0; s_E = 0; s_mg = 0xFFFFFFFFu; }
    __syncthreads();

    unsigned prefix = 0;
    unsigned r = jrel;
    for (int shift = 24; shift >= 0; shift -= 8) {
        hist[tid] = 0u;
        __syncthreads();
        for (unsigned i = tid; i < m; i += 256) {
            unsigned kk = keys[i];
            bool ok = (shift == 24) || ((kk >> (shift + 8)) == prefix);
            if (ok) atomicAdd(&hist[(kk >> shift) & 255u], 1u);
        }
        __syncthreads();
        if (tid < 64) {
            unsigned a0 = hist[tid*4+0], a1 = hist[tid*4+1];
            unsigned a2 = hist[tid*4+2], a3 = hist[tid*4+3];
            unsigned sum = a0 + a1 + a2 + a3;
            unsigned incv = sum;
            for (int d = 1; d < 64; d <<= 1) {
                unsigned y = __shfl_up(incv, d);
                if (tid >= d) incv += y;
            }
            unsigned excl = incv - sum;
            pfx[tid*4+0] = excl;
            pfx[tid*4+1] = excl + a0;
            pfx[tid*4+2] = excl + a0 + a1;
            pfx[tid*4+3] = excl + a0 + a1 + a2;
        }
        __syncthreads();
        {
            unsigned e = pfx[tid], c = hist[tid];
            if (e <= r && r < e + c) { s_bucket = tid; s_r = r - e; }
        }
        __syncthreads();
        prefix = (prefix << 8) | s_bucket;
        r = s_r;
        __syncthreads();
    }
    const unsigned vk = prefix;
    unsigned lL = 0, lE = 0, lmg = 0xFFFFFFFFu;
    for (unsigned i = tid; i < m; i += 256) {
        unsigned kk = keys[i];
        lL += (kk < vk) ? 1u : 0u;
        lE += (kk == vk) ? 1u : 0u;
        if (kk > vk && kk < lmg) lmg = kk;
    }
    atomicAdd(&s_L, lL);
    atomicAdd(&s_E, lE);
    atomicMin(&s_mg, lmg);
    __syncthreads();
    if (tid == 0) {
        unsigned vk1 = (jrel + 1 < s_L + s_E) ? vk : s_mg;
        float svk = keyf(vk), svk1 = keyf(vk1);
        const float idxf = 0.02f * (float)(HW - 1);
        const float frac = idxf - (float)((unsigned)idxf);   // 0.380859375
        ((float*)(ws + WS_LOHI))[s * 2 + 0] = svk * (1.0f - frac) + svk1 * frac;
    }
}

// main transform: normalize -> bin -> LUT gather -> write 3 channels (nontemporal)
__global__ __launch_bounds__(256) void k_apply(const float* __restrict__ x,
                                               const unsigned* __restrict__ ws,
                                               float* __restrict__ y) {
    __shared__ float slut[LBINS];
    const float* lutg = (const float*)(ws + WS_LUT);
    for (int i = threadIdx.x; i < LBINS; i += 256) slut[i] = lutg[i];
    const int s = blockIdx.y;
    const float* lh = (const float*)(ws + WS_LOHI);
    const float lo = lh[s * 2 + 0];
    const float hi = lh[s * 2 + 1];
    const float denom = hi - lo + EPSF;
    __syncthreads();
    const f32x4* xs = (const f32x4*)(x + (size_t)s * HW);
    f32x4* y0 = (f32x4*)(y + (size_t)s * 3 * HW);
    f32x4* y1 = (f32x4*)(y + (size_t)s * 3 * HW + HW);
    f32x4* y2 = (f32x4*)(y + (size_t)s * 3 * HW + 2 * HW);
    for (int i = blockIdx.x * 256 + threadIdx.x; i < N4; i += gridDim.x * 256) {
        f32x4 v = xs[i];
        f32x4 o;
#pragma unroll
        for (int c = 0; c < 4; ++c) {
            float xn = (v[c] - lo) / denom;
            xn = xn < 0.0f ? 0.0f : (xn > 1.0f ? 1.0f : xn);
            float t = xn * 2047.0f;
            int idx = (int)t;
            idx = idx < 0 ? 0 : (idx > 2047 ? 2047 : idx);
            o[c] = slut[idx];
        }
        __builtin_nontemporal_store(o, &y0[i]);
        __builtin_nontemporal_store(o, &y1[i]);
        __builtin_nontemporal_store(o, &y2[i]);
    }
}

extern "C" void kernel_launch(void* const* d_in, const int* in_sizes, int n_in,
                              void* d_out, int out_size, void* d_ws, size_t ws_size,
                              hipStream_t stream) {
    const float* x = (const float*)d_in[0];
    const float* delta = (const float*)d_in[1];
    float* y = (float*)d_out;
    unsigned* ws = (unsigned*)d_ws;

    int cap = CAPMAX;
    size_t avail_words = ws_size / 4;
    size_t per_sample = avail_words > WS_COLLECT ? (avail_words - WS_COLLECT) / NB : 0;
    if ((size_t)cap > per_sample) cap = (int)per_sample;

    k_hist<<<dim3(HBLK, NB), dim3(512), 0, stream>>>(x, ws);
    k_scan_lut<<<dim3(NB + 1), dim3(256), 0, stream>>>(ws, delta);
    k_collect<<<dim3(HBLK, NB), dim3(512), 0, stream>>>(x, ws, cap);
    k_select<<<dim3(NB), dim3(256), 0, stream>>>(ws, cap);
    k_apply<<<dim3(320, NB), dim3(256), 0, stream>>>(x, ws, y);
}

// Round 13
// 251.098 us; speedup vs baseline: 1.9041x; 1.1776x over previous
//
#include <hip/hip_runtime.h>
#include <hip/hip_bf16.h>
#include <math.h>

#define NB 8
#define HH 1024
#define WW 1280
#define HW (HH*WW)            // 1310720
#define N4 (HW/4)             // 327680
#define LBINS 2048
#define HBINS 2048
#define NSCENE 8
#define EPSF 1e-8f
#define CAPMAX 8192
#define HBLK 64               // hist/collect blocks per sample

typedef float f32x4 __attribute__((ext_vector_type(4)));
typedef unsigned short u16x8 __attribute__((ext_vector_type(8)));

// ws layout (32-bit word offsets) — no pre-zeroing required anywhere
// partials are u16: max per-bin count/block = 20480 < 65536
#define WS_PART        0                             // NB*HBLK*HBINS u16 (plain stores)
#define WS_PART_WORDS  (NB*HBLK*HBINS/2)             // 524288 words (2 MB)
#define WS_PMAX    (WS_PART + WS_PART_WORDS)         // NB*HBLK f32 per-block maxes
#define WS_INFO    (WS_PMAX + NB*HBLK)               // NB*4 u32 {t1, t2, jrel, pad}
#define WS_LOHI    (WS_INFO + NB*4)                  // NB*2 f32 {lo, hi}
#define WS_LUT     (WS_LOHI + NB*2)                  // 2048 f32
#define WS_CNT     (WS_LUT + LBINS)                  // NB u32 (zeroed by k_scan_lut)
#define WS_COLLECT (WS_CNT + NB)                     // NB*cap f32

__device__ __forceinline__ unsigned fkey(float f) {
    unsigned u = __float_as_uint(f);
    return (u & 0x80000000u) ? ~u : (u | 0x80000000u);
}
__device__ __forceinline__ float keyf(unsigned k) {
    unsigned u = (k & 0x80000000u) ? (k & 0x7fffffffu) : ~k;
    return __uint_as_float(u);
}

// per-sample 2048-bin histogram + block max -> u16 private partials.
__global__ __launch_bounds__(512) void k_hist(const float* __restrict__ x,
                                              unsigned* __restrict__ ws) {
    __shared__ unsigned lh[HBINS];
    __shared__ float redf[8];
    const int s = blockIdx.y;
    const int tid = threadIdx.x;
    for (int i = tid; i < HBINS; i += 512) lh[i] = 0u;
    __syncthreads();
    const float4* xs = (const float4*)(x + (size_t)s * HW);
    float mx = -3.4e38f;
    for (int i = blockIdx.x * 512 + tid; i < N4; i += HBLK * 512) {
        float4 v = xs[i];
        float fv[4] = {v.x, v.y, v.z, v.w};
#pragma unroll
        for (int c = 0; c < 4; ++c) {
            float f = fv[c];
            int b = (int)(f * 2048.0f);
            b = b < 0 ? 0 : (b > 2047 ? 2047 : b);
            atomicAdd(&lh[b], 1u);
            mx = fmaxf(mx, f);
        }
    }
    for (int d = 32; d > 0; d >>= 1) mx = fmaxf(mx, __shfl_down(mx, d));
    if ((tid & 63) == 0) redf[tid >> 6] = mx;
    __syncthreads();
    unsigned short* myp = (unsigned short*)(ws + WS_PART)
                          + ((size_t)s * HBLK + blockIdx.x) * HBINS;
    for (int i = tid; i < HBINS; i += 512) myp[i] = (unsigned short)lh[i];
    if (tid == 0) {
        float m2 = redf[0];
#pragma unroll
        for (int w = 1; w < 8; ++w) m2 = fmaxf(m2, redf[w]);
        ((float*)(ws + WS_PMAX))[s * HBLK + blockIdx.x] = m2;
    }
}

// blocks 0..7: per-sample partial-sum + prefix-scan -> target bins, jrel, hi, cnt=0
// block 8: LUT (softplus of scene-mean -> cumsum -> normalize to [-1,1])
__global__ __launch_bounds__(256) void k_scan_lut(unsigned* __restrict__ ws,
                                                  const float* __restrict__ delta) {
    __shared__ unsigned su[256];
    __shared__ float sf[256];
    const int s = blockIdx.x;
    const int tid = threadIdx.x;
    if (s == NB) {
        float inc[8];
        float run = 0.0f;
#pragma unroll
        for (int i = 0; i < 8; ++i) {
            int j = tid * 8 + i;
            float ssum = 0.0f;
#pragma unroll
            for (int sc = 0; sc < NSCENE; ++sc) ssum += delta[sc * LBINS + j];
            float v = ssum * 0.125f;
            run += fmaxf(v, 0.0f) + log1pf(expf(-fabsf(v))) + EPSF;   // softplus+eps
            inc[i] = run;   // local inclusive
        }
        sf[tid] = run;
        __syncthreads();
        for (int d = 1; d < 256; d <<= 1) {   // Hillis-Steele over thread totals
            float add = (tid >= d) ? sf[tid - d] : 0.0f;
            __syncthreads();
            sf[tid] += add;
            __syncthreads();
        }
        float excl = sf[tid] - run;
        float total = sf[255];
        float* lut = (float*)(ws + WS_LUT);
#pragma unroll
        for (int i = 0; i < 8; ++i)
            lut[tid * 8 + i] = (excl + inc[i]) / (total + EPSF) * 2.0f - 1.0f;
        return;
    }
    // sum 64 u16 partials per bin — one ushort8 (16B) load covers this thread's 8 bins
    const unsigned short* part = (const unsigned short*)(ws + WS_PART)
                                 + (size_t)s * HBLK * HBINS;
    unsigned cnt[8] = {0,0,0,0,0,0,0,0};
    for (int b = 0; b < HBLK; ++b) {
        u16x8 v = *(const u16x8*)(part + (size_t)b * HBINS + tid * 8);
#pragma unroll
        for (int i = 0; i < 8; ++i) cnt[i] += (unsigned)v[i];
    }
    unsigned run = 0u;
#pragma unroll
    for (int i = 0; i < 8; ++i) run += cnt[i];
    su[tid] = run;
    __syncthreads();
    for (int d = 1; d < 256; d <<= 1) {
        unsigned add = (tid >= d) ? su[tid - d] : 0u;
        __syncthreads();
        su[tid] += add;
        __syncthreads();
    }
    unsigned before = su[tid] - run;
    const float idxf = 0.02f * (float)(HW - 1);   // f32, mirrors JAX
    const unsigned k = (unsigned)idxf;            // 26214
#pragma unroll
    for (int i = 0; i < 8; ++i) {
        unsigned c = cnt[i];
        unsigned bin = tid * 8 + i;
        if (before <= k && k < before + c) {
            ws[WS_INFO + s * 4 + 0] = bin;
            ws[WS_INFO + s * 4 + 2] = k - before;   // rank of v[k] within collected
        }
        if (before <= k + 1 && k + 1 < before + c) {
            ws[WS_INFO + s * 4 + 1] = bin;
        }
        before += c;
    }
    if (tid < 64) {   // exactly wave 0: reduce block maxes -> hi
        float mx = ((const float*)(ws + WS_PMAX))[s * HBLK + tid];
        for (int d = 32; d > 0; d >>= 1) mx = fmaxf(mx, __shfl_down(mx, d));
        if (tid == 0) {
            ((float*)(ws + WS_LOHI))[s * 2 + 1] = mx;
            ws[WS_CNT + s] = 0u;
        }
    }
}

// gather elements in target bin range (x re-read is L2/L3-resident). 512-thread blocks.
__global__ __launch_bounds__(512) void k_collect(const float* __restrict__ x,
                                                 unsigned* __restrict__ ws, int cap) {
    const int s = blockIdx.y;
    const unsigned t1 = ws[WS_INFO + s * 4 + 0];
    const unsigned t2 = ws[WS_INFO + s * 4 + 1];
    float* coll = (float*)(ws + WS_COLLECT) + (size_t)s * cap;
    unsigned* cnt = ws + WS_CNT + s;
    const float4* xs = (const float4*)(x + (size_t)s * HW);
    for (int i = blockIdx.x * 512 + threadIdx.x; i < N4; i += HBLK * 512) {
        float4 v = xs[i];
        float fv[4] = {v.x, v.y, v.z, v.w};
#pragma unroll
        for (int c = 0; c < 4; ++c) {
            float f = fv[c];
            int b = (int)(f * 2048.0f);
            b = b < 0 ? 0 : (b > 2047 ? 2047 : b);
            if ((unsigned)b >= t1 && (unsigned)b <= t2) {
                unsigned p = atomicAdd(cnt, 1u);
                if (p < (unsigned)cap) coll[p] = f;
            }
        }
    }
}

// exact selection via 4-pass byte-radix, then v[k+1] pass; writes lo
__global__ __launch_bounds__(256) void k_select(unsigned* __restrict__ ws, int cap) {
    __shared__ unsigned keys[CAPMAX];
    __shared__ unsigned hist[256];
    __shared__ unsigned pfx[256];
    __shared__ unsigned s_bucket, s_r;
    __shared__ unsigned s_L, s_E, s_mg;
    const int s = blockIdx.x;
    const int tid = threadIdx.x;
    unsigned m = ws[WS_CNT + s];
    if (m > (unsigned)cap) m = (unsigned)cap;
    const float* coll = (const float*)(ws + WS_COLLECT) + (size_t)s * cap;
    const unsigned jrel = ws[WS_INFO + s * 4 + 2];

    for (unsigned i = tid; i < m; i += 256) keys[i] = fkey(coll[i]);
    if (tid == 0) { s_L = 0; s_E = 0; s_mg = 0xFFFFFFFFu; }
    __syncthreads();

    unsigned prefix = 0;
    unsigned r = jrel;
    for (int shift = 24; shift >= 0; shift -= 8) {
        hist[tid] = 0u;
        __syncthreads();
        for (unsigned i = tid; i < m; i += 256) {
            unsigned kk = keys[i];
            bool ok = (shift == 24) || ((kk >> (shift + 8)) == prefix);
            if (ok) atomicAdd(&hist[(kk >> shift) & 255u], 1u);
        }
        __syncthreads();
        if (tid < 64) {
            unsigned a0 = hist[tid*4+0], a1 = hist[tid*4+1];
            unsigned a2 = hist[tid*4+2], a3 = hist[tid*4+3];
            unsigned sum = a0 + a1 + a2 + a3;
            unsigned incv = sum;
            for (int d = 1; d < 64; d <<= 1) {
                unsigned y = __shfl_up(incv, d);
                if (tid >= d) incv += y;
            }
            unsigned excl = incv - sum;
            pfx[tid*4+0] = excl;
            pfx[tid*4+1] = excl + a0;
            pfx[tid*4+2] = excl + a0 + a1;
            pfx[tid*4+3] = excl + a0 + a1 + a2;
        }
        __syncthreads();
        {
            unsigned e = pfx[tid], c = hist[tid];
            if (e <= r && r < e + c) { s_bucket = tid; s_r = r - e; }
        }
        __syncthreads();
        prefix = (prefix << 8) | s_bucket;
        r = s_r;
        __syncthreads();
    }
    const unsigned vk = prefix;
    unsigned lL = 0, lE = 0, lmg = 0xFFFFFFFFu;
    for (unsigned i = tid; i < m; i += 256) {
        unsigned kk = keys[i];
        lL += (kk < vk) ? 1u : 0u;
        lE += (kk == vk) ? 1u : 0u;
        if (kk > vk && kk < lmg) lmg = kk;
    }
    atomicAdd(&s_L, lL);
    atomicAdd(&s_E, lE);
    atomicMin(&s_mg, lmg);
    __syncthreads();
    if (tid == 0) {
        unsigned vk1 = (jrel + 1 < s_L + s_E) ? vk : s_mg;
        float svk = keyf(vk), svk1 = keyf(vk1);
        const float idxf = 0.02f * (float)(HW - 1);
        const float frac = idxf - (float)((unsigned)idxf);   // 0.380859375
        ((float*)(ws + WS_LOHI))[s * 2 + 0] = svk * (1.0f - frac) + svk1 * frac;
    }
}

// main transform: normalize -> bin -> LUT gather -> write 3 channels (nontemporal)
__global__ __launch_bounds__(256) void k_apply(const float* __restrict__ x,
                                               const unsigned* __restrict__ ws,
                                               float* __restrict__ y) {
    __shared__ float slut[LBINS];
    const float* lutg = (const float*)(ws + WS_LUT);
    for (int i = threadIdx.x; i < LBINS; i += 256) slut[i] = lutg[i];
    const int s = blockIdx.y;
    const float* lh = (const float*)(ws + WS_LOHI);
    const float lo = lh[s * 2 + 0];
    const float hi = lh[s * 2 + 1];
    const float denom = hi - lo + EPSF;
    __syncthreads();
    const f32x4* xs = (const f32x4*)(x + (size_t)s * HW);
    f32x4* y0 = (f32x4*)(y + (size_t)s * 3 * HW);
    f32x4* y1 = (f32x4*)(y + (size_t)s * 3 * HW + HW);
    f32x4* y2 = (f32x4*)(y + (size_t)s * 3 * HW + 2 * HW);
    for (int i = blockIdx.x * 256 + threadIdx.x; i < N4; i += gridDim.x * 256) {
        f32x4 v = xs[i];
        f32x4 o;
#pragma unroll
        for (int c = 0; c < 4; ++c) {
            float xn = (v[c] - lo) / denom;
            xn = xn < 0.0f ? 0.0f : (xn > 1.0f ? 1.0f : xn);
            float t = xn * 2047.0f;
            int idx = (int)t;
            idx = idx < 0 ? 0 : (idx > 2047 ? 2047 : idx);
            o[c] = slut[idx];
        }
        __builtin_nontemporal_store(o, &y0[i]);
        __builtin_nontemporal_store(o, &y1[i]);
        __builtin_nontemporal_store(o, &y2[i]);
    }
}

extern "C" void kernel_launch(void* const* d_in, const int* in_sizes, int n_in,
                              void* d_out, int out_size, void* d_ws, size_t ws_size,
                              hipStream_t stream) {
    const float* x = (const float*)d_in[0];
    const float* delta = (const float*)d_in[1];
    float* y = (float*)d_out;
    unsigned* ws = (unsigned*)d_ws;

    int cap = CAPMAX;
    size_t avail_words = ws_size / 4;
    size_t per_sample = avail_words > WS_COLLECT ? (avail_words - WS_COLLECT) / NB : 0;
    if ((size_t)cap > per_sample) cap = (int)per_sample;

    k_hist<<<dim3(HBLK, NB), dim3(512), 0, stream>>>(x, ws);
    k_scan_lut<<<dim3(NB + 1), dim3(256), 0, stream>>>(ws, delta);
    k_collect<<<dim3(HBLK, NB), dim3(512), 0, stream>>>(x, ws, cap);
    k_select<<<dim3(NB), dim3(256), 0, stream>>>(ws, cap);
    k_apply<<<dim3(320, NB), dim3(256), 0, stream>>>(x, ws, y);
}